// Round 1
// baseline (87.003 us; speedup 1.0000x reference)
//
#include <hip/hip_runtime.h>

// GatingRouting: alpha = blend(softmax(relu(o/150 * W1 + b1) @ W2 + b2), o)
//   o >= 100  -> (0,0,1)
//   o <= 10   -> (p0,p1,0)/(p0+p1)   == (e0,e1,0)/(e0+e1)  (softmax scale cancels)
//   else      -> softmax
// BATCH = 2^21 rows, HIDDEN = 64, out (BATCH,3) fp32.

#define HIDDEN 64
constexpr int R = 8;        // rows per thread: hoists the 64-dim weight loop over 8 rows
constexpr int BLOCK = 256;  // rows per block = 2048 -> grid 1024

__global__ __launch_bounds__(BLOCK) void gating_kernel(
    const float* __restrict__ o_batch,
    const float* __restrict__ W1,
    const float* __restrict__ b1,
    const float* __restrict__ W2,   // (64,3) row-major
    const float* __restrict__ b2,   // (3,)
    float* __restrict__ out,        // (BATCH,3) row-major
    int batch)
{
    __shared__ float2 s_wb[HIDDEN];  // (w1_j, b1_j)
    __shared__ float4 s_w2[HIDDEN];  // (W2[j][0..2], pad)

    const int tid = threadIdx.x;
    if (tid < HIDDEN) {
        s_wb[tid] = make_float2(W1[tid], b1[tid]);
        s_w2[tid] = make_float4(W2[3 * tid], W2[3 * tid + 1], W2[3 * tid + 2], 0.f);
    }
    const float bb0 = b2[0], bb1 = b2[1], bb2 = b2[2];
    __syncthreads();

    const long long base = (long long)blockIdx.x * (BLOCK * R) + (long long)tid * R;

    // 8 contiguous o values per thread: two aligned float4 loads (base % 8 == 0)
    const float4* op = (const float4*)(o_batch + base);
    const float4 o03 = op[0], o47 = op[1];
    float o[R] = {o03.x, o03.y, o03.z, o03.w, o47.x, o47.y, o47.z, o47.w};

    float x[R], a0[R], a1[R], a2[R];
#pragma unroll
    for (int r = 0; r < R; r++) {
        x[r] = o[r] * (1.0f / 150.0f);
        a0[r] = bb0; a1[r] = bb1; a2[r] = bb2;
    }

#pragma unroll 8
    for (int j = 0; j < HIDDEN; j++) {
        const float2 wb = s_wb[j];   // broadcast ds_read_b64 (conflict-free)
        const float4 w2 = s_w2[j];   // broadcast ds_read_b128
#pragma unroll
        for (int r = 0; r < R; r++) {
            const float h = fmaxf(fmaf(x[r], wb.x, wb.y), 0.0f);
            a0[r] = fmaf(h, w2.x, a0[r]);
            a1[r] = fmaf(h, w2.y, a1[r]);
            a2[r] = fmaf(h, w2.z, a2[r]);
        }
    }

    float res[R * 3];
#pragma unroll
    for (int r = 0; r < R; r++) {
        const float m = fmaxf(a0[r], fmaxf(a1[r], a2[r]));
        const float e0 = __expf(a0[r] - m);
        const float e1 = __expf(a1[r] - m);
        const float e2 = __expf(a2[r] - m);
        const float inv = __builtin_amdgcn_rcpf(e0 + e1 + e2);
        float p0 = e0 * inv, p1 = e1 * inv, p2 = e2 * inv;
        const float oo = o[r];
        if (oo >= 100.0f) {
            p0 = 0.f; p1 = 0.f; p2 = 1.f;
        } else if (oo <= 10.0f) {
            const float inv12 = __builtin_amdgcn_rcpf(e0 + e1);
            p0 = e0 * inv12; p1 = e1 * inv12; p2 = 0.f;
        }
        res[3 * r + 0] = p0; res[3 * r + 1] = p1; res[3 * r + 2] = p2;
    }

    // 24 contiguous output floats per thread = 6 float4 stores (96B-aligned base)
    float4* outp = (float4*)(out + base * 3);
#pragma unroll
    for (int i = 0; i < 6; i++) {
        outp[i] = make_float4(res[4 * i], res[4 * i + 1], res[4 * i + 2], res[4 * i + 3]);
    }
}

extern "C" void kernel_launch(void* const* d_in, const int* in_sizes, int n_in,
                              void* d_out, int out_size, void* d_ws, size_t ws_size,
                              hipStream_t stream) {
    const float* o_batch = (const float*)d_in[0];
    const float* W1      = (const float*)d_in[1];
    const float* b1      = (const float*)d_in[2];
    const float* W2      = (const float*)d_in[3];
    const float* b2      = (const float*)d_in[4];
    float* out = (float*)d_out;

    const int batch = in_sizes[0];            // 2097152
    const int grid = batch / (BLOCK * R);     // 1024 (exact)
    gating_kernel<<<grid, BLOCK, 0, stream>>>(o_batch, W1, b1, W2, b2, out, batch);
}